// Round 2
// baseline (633.339 us; speedup 1.0000x reference)
//
#include <hip/hip_runtime.h>
#include <math.h>

// Problem constants: x shape (B=4, C=8, D=16, H=256, W=256), k=3x3x3, stride 1, pad 1.
#define BC 32
#define DD 16
#define HH 256
#define WW 256
#define PLANE (HH * WW)              // 65536
#define CH_ELEMS (DD * PLANE)        // 1048576
#define COORD_ELEMS (BC * 3 * CH_ELEMS)  // 100663296
#define TS 68                        // LDS row stride (66 used + pad, 16B-aligned rows)

typedef float vf4 __attribute__((ext_vector_type(4)));

// ---------------- Pass 1: per-channel max ----------------
__global__ __launch_bounds__(256) void chmax_part(const float* __restrict__ x,
                                                  float* __restrict__ part) {
    const int ch = blockIdx.y;
    const int tid = threadIdx.x;
    const float4* p4 = (const float4*)(x + (size_t)ch * CH_ELEMS) + (size_t)blockIdx.x * 4096;
    float m = -3.402823466e38f;
#pragma unroll
    for (int i = 0; i < 16; ++i) {
        float4 v = p4[tid + i * 256];
        m = fmaxf(m, fmaxf(fmaxf(v.x, v.y), fmaxf(v.z, v.w)));
    }
#pragma unroll
    for (int off = 32; off > 0; off >>= 1)
        m = fmaxf(m, __shfl_down(m, off, 64));
    __shared__ float sm[4];
    if ((tid & 63) == 0) sm[tid >> 6] = m;
    __syncthreads();
    if (tid == 0)
        part[ch * 64 + blockIdx.x] = fmaxf(fmaxf(sm[0], sm[1]), fmaxf(sm[2], sm[3]));
}

__global__ __launch_bounds__(64) void chmax_final(const float* __restrict__ part,
                                                  float* __restrict__ mx) {
    const int ch = blockIdx.x, tid = threadIdx.x;
    float m = part[ch * 64 + tid];
#pragma unroll
    for (int off = 32; off > 0; off >>= 1)
        m = fmaxf(m, __shfl_down(m, off, 64));
    if (tid == 0) mx[ch] = m;
}

// ---------------- Pass 2: fused conv-soft-argmax ----------------
// Block: 256 threads. Tile: 16 h x 64 w, full D loop, one channel (blockIdx.z).
// Thread (hl = tid>>4, wb = (tid&15)*4) owns 4 consecutive w outputs for all d.
__global__ __launch_bounds__(256) void csam3d_main(const float* __restrict__ xin_all,
                                                   const float* __restrict__ mx,
                                                   float* __restrict__ out) {
    const int ch = blockIdx.z;
    const int h0 = blockIdx.y * 16;
    const int w0 = blockIdx.x * 64;
    const int tid = threadIdx.x;
    const float cmax = mx[ch];
    const float* __restrict__ xin = xin_all + (size_t)ch * CH_ELEMS;

    float* __restrict__ outz = out + (size_t)(ch * 3 + 0) * CH_ELEMS;
    float* __restrict__ outx = out + (size_t)(ch * 3 + 1) * CH_ELEMS;
    float* __restrict__ outy = out + (size_t)(ch * 3 + 2) * CH_ELEMS;
    float* __restrict__ outv = out + COORD_ELEMS + (size_t)ch * CH_ELEMS;

    __shared__ __align__(16) float eS[2][18 * TS];  // exp(x - cmax), zero-padded halo
    __shared__ __align__(16) float vS[2][18 * TS];  // e * x

    const int hl = tid >> 4;          // 0..15
    const int wb = (tid & 15) << 2;   // 0,4,...,60

    // 3-slot ring of per-slice 2D window stats, 4 w-outputs each
    float s2[3][4], mx2[3][4], my2[3][4], sv2[3][4];

// Stage slice I (input depth din = I-1; out-of-range depth -> zeros) into buffer I&1.
#define STAGE(I) do {                                                         \
    const int din_ = (I) - 1;                                                 \
    float* eb_ = eS[(I) & 1];                                                 \
    float* vb_ = vS[(I) & 1];                                                 \
    if (din_ < 0 || din_ >= DD) {                                             \
        for (int s5 = tid; s5 < 18 * TS; s5 += 256) { eb_[s5] = 0.f; vb_[s5] = 0.f; } \
    } else {                                                                  \
        const float* xp_ = xin + (size_t)din_ * PLANE;                        \
        _Pragma("unroll")                                                     \
        for (int it = 0; it < 5; ++it) {                                      \
            int s5 = tid + it * 256;                                          \
            if (s5 < 18 * 66) {                                               \
                int lh = s5 / 66;                                             \
                int lw = s5 - lh * 66;                                        \
                int gh = h0 + lh - 1;                                         \
                int gw = w0 + lw - 1;                                         \
                float ev = 0.f, vv = 0.f;                                     \
                if ((unsigned)gh < (unsigned)HH && (unsigned)gw < (unsigned)WW) { \
                    float xv = xp_[gh * WW + gw];                             \
                    ev = __expf(xv - cmax);                                   \
                    vv = ev * xv;                                             \
                }                                                             \
                eb_[lh * TS + lw] = ev;                                       \
                vb_[lh * TS + lw] = vv;                                       \
            }                                                                 \
        }                                                                     \
    }                                                                         \
} while (0)

#define LDROW(PTR) do {                                                       \
    float4 a_ = *(const float4*)(PTR);                                        \
    float2 b_ = *(const float2*)((PTR) + 4);                                  \
    v0 = a_.x; v1 = a_.y; v2 = a_.z; v3 = a_.w; v4 = b_.x; v5 = b_.y;         \
} while (0)

// Compute 2D (h,w) window stats for slice I into ring slot SC.
#define CSLICE(I, SC) do {                                                    \
    const float* eb_ = eS[(I) & 1] + hl * TS + wb;                            \
    const float* vb_ = vS[(I) & 1] + hl * TS + wb;                            \
    float v0, v1, v2, v3, v4, v5;                                             \
    LDROW(eb_);                                                               \
    float c0 = v0, c1 = v1, c2 = v2, c3 = v3, c4 = v4, c5 = v5;               \
    float d0 = -v0, d1 = -v1, d2 = -v2, d3 = -v3, d4 = -v4, d5 = -v5;         \
    LDROW(eb_ + TS);                                                          \
    c0 += v0; c1 += v1; c2 += v2; c3 += v3; c4 += v4; c5 += v5;               \
    LDROW(eb_ + 2 * TS);                                                      \
    c0 += v0; c1 += v1; c2 += v2; c3 += v3; c4 += v4; c5 += v5;               \
    d0 += v0; d1 += v1; d2 += v2; d3 += v3; d4 += v4; d5 += v5;               \
    LDROW(vb_);                                                               \
    float g0 = v0, g1 = v1, g2 = v2, g3 = v3, g4 = v4, g5 = v5;               \
    LDROW(vb_ + TS);                                                          \
    g0 += v0; g1 += v1; g2 += v2; g3 += v3; g4 += v4; g5 += v5;               \
    LDROW(vb_ + 2 * TS);                                                      \
    g0 += v0; g1 += v1; g2 += v2; g3 += v3; g4 += v4; g5 += v5;               \
    s2[SC][0] = c0 + c1 + c2;  s2[SC][1] = c1 + c2 + c3;                      \
    s2[SC][2] = c2 + c3 + c4;  s2[SC][3] = c3 + c4 + c5;                      \
    mx2[SC][0] = c2 - c0; mx2[SC][1] = c3 - c1;                               \
    mx2[SC][2] = c4 - c2; mx2[SC][3] = c5 - c3;                               \
    my2[SC][0] = d0 + d1 + d2;  my2[SC][1] = d1 + d2 + d3;                    \
    my2[SC][2] = d2 + d3 + d4;  my2[SC][3] = d3 + d4 + d5;                    \
    sv2[SC][0] = g0 + g1 + g2;  sv2[SC][1] = g1 + g2 + g3;                    \
    sv2[SC][2] = g2 + g3 + g4;  sv2[SC][3] = g3 + g4 + g5;                    \
} while (0)

// Emit output depth dout = I-2 combining ring slots SA (d-1), SB (d), SC (d+1).
#define EMIT(I, SA, SB, SC) do {                                              \
    const int dout_ = (I) - 2;                                                \
    vf4 oz, ox, oy, ov;                                                       \
    _Pragma("unroll")                                                         \
    for (int k = 0; k < 4; ++k) {                                             \
        float S  = s2[SA][k] + s2[SB][k] + s2[SC][k];                         \
        float Mz = s2[SC][k] - s2[SA][k];                                     \
        float Mx = mx2[SA][k] + mx2[SB][k] + mx2[SC][k];                      \
        float My = my2[SA][k] + my2[SB][k] + my2[SC][k];                      \
        float Sv = sv2[SA][k] + sv2[SB][k] + sv2[SC][k];                      \
        float inv = __builtin_amdgcn_rcpf(S + 1e-8f);                         \
        oz[k] = Mz * inv + (float)dout_;                                      \
        ox[k] = Mx * inv + (float)(w0 + wb + k);                              \
        oy[k] = My * inv + (float)(h0 + hl);                                  \
        ov[k] = Sv * inv;                                                     \
    }                                                                         \
    size_t off_ = (size_t)dout_ * PLANE + (size_t)(h0 + hl) * WW + (w0 + wb); \
    __builtin_nontemporal_store(oz, (vf4*)(outz + off_));                     \
    __builtin_nontemporal_store(ox, (vf4*)(outx + off_));                     \
    __builtin_nontemporal_store(oy, (vf4*)(outy + off_));                     \
    __builtin_nontemporal_store(ov, (vf4*)(outv + off_));                     \
} while (0)

#define STEP(I, SC, SA, SB) do {                                              \
    STAGE(I);                                                                 \
    __syncthreads();                                                          \
    CSLICE(I, SC);                                                            \
    if ((I) >= 2) EMIT(I, SA, SB, SC);                                        \
} while (0)

    for (int ii = 0; ii < 18; ii += 3) {
        STEP(ii + 0, 0, 1, 2);
        STEP(ii + 1, 1, 2, 0);
        STEP(ii + 2, 2, 0, 1);
    }
}

extern "C" void kernel_launch(void* const* d_in, const int* in_sizes, int n_in,
                              void* d_out, int out_size, void* d_ws, size_t ws_size,
                              hipStream_t stream) {
    const float* x = (const float*)d_in[0];
    float* out = (float*)d_out;
    float* part = (float*)d_ws;      // 2048 floats
    float* mx = part + 2048;         // 32 floats

    chmax_part<<<dim3(64, 32), 256, 0, stream>>>(x, part);
    chmax_final<<<32, 64, 0, stream>>>(part, mx);
    csam3d_main<<<dim3(4, 16, 32), 256, 0, stream>>>(x, mx, out);
}